// Round 15
// baseline (284.979 us; speedup 1.0000x reference)
//
#include <hip/hip_runtime.h>

#define E     1024
#define HEADS 16
#define HD    64
#define FFD   4096
#define TT    2048
#define MMDIM 4096   // B*T
#define NKV   1024   // KV per attention part (split 2)
#define PO    (32 * 2048 * 64)  // elems per attn O-partial

typedef __bf16 bf16x8 __attribute__((ext_vector_type(8)));
typedef float f32x4 __attribute__((ext_vector_type(4)));
typedef float f32x16 __attribute__((ext_vector_type(16)));
typedef unsigned short u16;
typedef unsigned u32;
typedef u16 ushort8 __attribute__((ext_vector_type(8)));
typedef u16 us4 __attribute__((ext_vector_type(4)));
typedef u32 u32x4 __attribute__((ext_vector_type(4)));

__device__ __forceinline__ u16 f2bf(float f) {
  unsigned u = __float_as_uint(f);
  u = (u + 0x7fffu + ((u >> 16) & 1u)) >> 16;
  return (u16)u;
}
__device__ __forceinline__ float bf2f(u16 u) {
  return __uint_as_float(((unsigned)u) << 16);
}
__device__ __forceinline__ u32 cvtpk(float a, float b) {
  u32 r;
  asm("v_cvt_pk_bf16_f32 %0, %1, %2" : "=v"(r) : "v"(a), "v"(b));
  return r;
}

__device__ __forceinline__ void gload_lds16(const void* g, void* l) {
  __builtin_amdgcn_global_load_lds((__attribute__((address_space(1))) void*)g,
                                   (__attribute__((address_space(3))) void*)l,
                                   16, 0, 0);
}

// ---------------- LayerNorm: fp32 in -> bf16 out ----------------
__global__ void __launch_bounds__(256) ln_kernel(const float* __restrict__ x,
                                                 const float* __restrict__ g,
                                                 const float* __restrict__ b,
                                                 u16* __restrict__ out) {
  int row = blockIdx.x;
  int t = threadIdx.x;
  const float4 v = reinterpret_cast<const float4*>(x + (size_t)row * E)[t];
  float s = v.x + v.y + v.z + v.w;
  float s2 = v.x * v.x + v.y * v.y + v.z * v.z + v.w * v.w;
#pragma unroll
  for (int m = 1; m < 64; m <<= 1) {
    s += __shfl_xor(s, m);
    s2 += __shfl_xor(s2, m);
  }
  __shared__ float red[8];
  int wave = t >> 6, lane = t & 63;
  if (lane == 0) { red[wave] = s; red[wave + 4] = s2; }
  __syncthreads();
  s = red[0] + red[1] + red[2] + red[3];
  s2 = red[4] + red[5] + red[6] + red[7];
  float mean = s * (1.f / E);
  float var = s2 * (1.f / E) - mean * mean;
  float inv = rsqrtf(var + 1e-5f);
  const float4 gv = reinterpret_cast<const float4*>(g)[t];
  const float4 bv = reinterpret_cast<const float4*>(b)[t];
  us4 pk;
  pk.x = f2bf((v.x - mean) * inv * gv.x + bv.x);
  pk.y = f2bf((v.y - mean) * inv * gv.y + bv.y);
  pk.z = f2bf((v.z - mean) * inv * gv.z + bv.z);
  pk.w = f2bf((v.w - mean) * inv * gv.w + bv.w);
  *(us4*)(out + (size_t)row * E + t * 4) = pk;
}

// ------- Fused transpose+convert of all 4 weights: W[K,N] fp32 -> bf16 [N,K]
__global__ void __launch_bounds__(256) transpose4(const float* __restrict__ w0,
                                                  const float* __restrict__ w1,
                                                  const float* __restrict__ w2,
                                                  const float* __restrict__ w3,
                                                  u16* __restrict__ o0,
                                                  u16* __restrict__ o1,
                                                  u16* __restrict__ o2,
                                                  u16* __restrict__ o3) {
  __shared__ float tile[32][33];
  int b = blockIdx.x;
  const float* in;
  u16* out;
  int K, N, bx, by;
  if (b < 3072) {            // qkv_w 1024x3072
    in = w0; out = o0; K = 1024; N = 3072; bx = b % 96; by = b / 96;
  } else if (b < 4096) {     // out_w 1024x1024
    int r = b - 3072; in = w1; out = o1; K = 1024; N = 1024; bx = r % 32; by = r / 32;
  } else if (b < 8192) {     // ff_w1 1024x4096
    int r = b - 4096; in = w2; out = o2; K = 1024; N = 4096; bx = r % 128; by = r / 128;
  } else {                   // ff_w2 4096x1024
    int r = b - 8192; in = w3; out = o3; K = 4096; N = 1024; bx = r % 32; by = r / 32;
  }
  int k0 = by * 32, n0 = bx * 32;
  int tx = threadIdx.x, ty = threadIdx.y;  // block (32,8)
#pragma unroll
  for (int i = ty; i < 32; i += 8)
    tile[i][tx] = in[(size_t)(k0 + i) * N + n0 + tx];
  __syncthreads();
#pragma unroll
  for (int i = ty; i < 32; i += 8)
    out[(size_t)(n0 + i) * K + k0 + tx] = f2bf(tile[tx][i]);
}

// ========== 2-phase GEMM, WIDE tile 128x256, BK=32, 48 KiB LDS ==========
// C[M,N] = A[M,K]bf16 @ Bt[N,K]bf16^T. 512 thr (8 waves, 2Mx4N of 64x64),
// double-buffered 2-phase (STAGE(t+1) before compute(t), one vmcnt(0)+
// s_barrier per step). Staged bytes ∝ (1/BM + 1/BN): 25% less than 128x128.
// LDS rows 64B; swizzle slot' = hi4 ^ (l15&3) ^ ((l15>>2)&3) (2-way max,
// free), pre-swizzled global source (rule 21). 4x8 super-tile XCD map
// (needs gx%4==0, gy%8==0 -- all our grids).
// MODE 0: +qkv_b, scatter Q(*0.125)/K -> [BH,T,D], V -> [BH,D,T]
// MODE 2: +ff_b1, exact GELU -> bf16 ob0 (stride FFD)
// MODE 3: split-K: z==0 -> of = acc+bias+resid (fp32); z==1 -> bf16 partial ob0
template <int MODE>
__global__ void __launch_bounds__(512) gemm2pw(const u16* __restrict__ Aa,
                                               const u16* __restrict__ Bt,
                                               const float* __restrict__ bias,
                                               const float* __restrict__ resid,
                                               u16* __restrict__ ob0,
                                               u16* __restrict__ ob1,
                                               u16* __restrict__ ob2,
                                               float* __restrict__ of,
                                               int N, int K, int lda, int ldb) {
  __shared__ __align__(16) u16 As[2][128 * 32];
  __shared__ __align__(16) u16 Bs[2][256 * 32];
  // 4x8 super-tile XCD mapping (bijective)
  const int gx = gridDim.x;
  const int nxy = gx * gridDim.y;
  const int lin = blockIdx.y * gx + blockIdx.x;
  const int g = (lin & 7) * (nxy >> 3) + (lin >> 3);
  const int s = g >> 5, o = g & 31;
  const int gx4 = gx >> 2;
  const int sx = s % gx4, sy = s / gx4;
  const int n0 = (sx * 4 + (o & 3)) * 256;
  const int m0 = (sy * 8 + (o >> 2)) * 128;
  const int tid = threadIdx.x, lane = tid & 63;
  const int w = tid >> 6, wr = w >> 2, wc = w & 3;
  const int l15 = lane & 15, hi4 = lane >> 4;
  const size_t koff = (size_t)blockIdx.z * K;
  const int nt = K >> 5;

  f32x4 acc[4][4];
#pragma unroll
  for (int i = 0; i < 4; i++)
#pragma unroll
    for (int j = 0; j < 4; j++) acc[i][j] = (f32x4){0.f, 0.f, 0.f, 0.f};

  // staging: A has 512 16B-chunks (1/thread), B has 1024 (2/thread)
  const int arow = tid >> 2, aslot = tid & 3;
  const int asw = (arow & 3) ^ ((arow >> 2) & 3);  // same for brow+128
  const int brow1 = arow + 128;
  const u16* Ap = Aa + (size_t)(m0 + arow) * lda + koff + (aslot ^ asw) * 8;
  const u16* Bq0 = Bt + (size_t)(n0 + arow) * ldb + koff + (aslot ^ asw) * 8;
  const u16* Bq1 = Bt + (size_t)(n0 + brow1) * ldb + koff + (aslot ^ asw) * 8;

  // ds_read lane constants: row&3 == l15&3, (row>>2)&3 == (l15>>2)&3
  const int rsw = (l15 & 3) ^ ((l15 >> 2) & 3);
  const int rdofs = (hi4 ^ rsw) << 4;

#define STAGEW(T, BUF)                                                         \
  do {                                                                         \
    int k0_ = (T) << 5;                                                        \
    gload_lds16(Ap + k0_, (char*)&As[BUF][0] + tid * 16);                      \
    gload_lds16(Bq0 + k0_, (char*)&Bs[BUF][0] + tid * 16);                     \
    gload_lds16(Bq1 + k0_, (char*)&Bs[BUF][0] + (tid + 512) * 16);             \
  } while (0)

  STAGEW(0, 0);
  asm volatile("s_waitcnt vmcnt(0)" ::: "memory");
  __builtin_amdgcn_s_barrier();
  __builtin_amdgcn_sched_barrier(0);

  for (int t = 0; t < nt; ++t) {
    const int cur = t & 1;
    if (t + 1 < nt) {
      if (cur == 0) STAGEW(t + 1, 1);
      else          STAGEW(t + 1, 0);
    }
    const char* ab = (const char*)&As[cur][0];
    const char* bb = (const char*)&Bs[cur][0];
    bf16x8 a[4], b[4];
#pragma unroll
    for (int i = 0; i < 4; i++)
      a[i] = *(const bf16x8*)(ab + (wr * 64 + i * 16 + l15) * 64 + rdofs);
#pragma unroll
    for (int j = 0; j < 4; j++)
      b[j] = *(const bf16x8*)(bb + (wc * 64 + j * 16 + l15) * 64 + rdofs);
    asm volatile("s_waitcnt lgkmcnt(0)" ::: "memory");
    __builtin_amdgcn_sched_barrier(0);
    __builtin_amdgcn_s_setprio(1);
#pragma unroll
    for (int i = 0; i < 4; i++)
#pragma unroll
      for (int j = 0; j < 4; j++)
        acc[i][j] = __builtin_amdgcn_mfma_f32_16x16x32_bf16(a[i], b[j], acc[i][j], 0, 0, 0);
    __builtin_amdgcn_s_setprio(0);
    asm volatile("s_waitcnt vmcnt(0)" ::: "memory");
    __builtin_amdgcn_s_barrier();
    __builtin_amdgcn_sched_barrier(0);
  }
#undef STAGEW

  // -------- epilogue --------
#pragma unroll
  for (int i = 0; i < 4; i++) {
#pragma unroll
    for (int j = 0; j < 4; j++) {
      int mb = m0 + wr * 64 + i * 16 + (hi4 << 2);
      int n = n0 + wc * 64 + j * 16 + l15;
      float bv = (MODE == 3) ? 0.f : bias[n];
      float v4[4];
#pragma unroll
      for (int r = 0; r < 4; r++) v4[r] = acc[i][j][r] + bv;
      if (MODE == 0) {
        int b_ = mb >> 11;
        int t = mb & 2047;
        int s_ = n >> 10;
        int hd = n & 1023;
        int h_ = hd >> 6;
        int d = hd & 63;
        size_t bh = (size_t)b_ * HEADS + h_;
        if (s_ == 0) {
#pragma unroll
          for (int r = 0; r < 4; r++)
            ob0[(bh * TT + (t + r)) * HD + d] = f2bf(v4[r] * 0.125f);
        } else if (s_ == 1) {
#pragma unroll
          for (int r = 0; r < 4; r++)
            ob1[(bh * TT + (t + r)) * HD + d] = f2bf(v4[r]);
        } else {
          us4 pk;
#pragma unroll
          for (int r = 0; r < 4; r++) pk[r] = f2bf(v4[r]);
          *(us4*)&ob2[(bh * HD + d) * TT + t] = pk;
        }
      } else if (MODE == 2) {  // exact GELU
#pragma unroll
        for (int r = 0; r < 4; r++)
          ob0[(size_t)(mb + r) * FFD + n] =
              f2bf(0.5f * v4[r] * (1.f + erff(v4[r] * 0.70710678118f)));
      } else {  // MODE 3: split-K
        if (blockIdx.z == 0) {
          float bz = bias[n];
#pragma unroll
          for (int r = 0; r < 4; r++) {
            size_t idx = (size_t)(mb + r) * E + n;
            of[idx] = v4[r] + bz + resid[idx];
          }
        } else {
#pragma unroll
          for (int r = 0; r < 4; r++)
            ob0[(size_t)(mb + r) * N + n] = f2bf(v4[r]);
        }
      }
    }
  }
}

// ------------- split-K reduce: out += p (fp32 out, bf16 partial) -------------
__global__ void __launch_bounds__(256) addp_reduce(const u16* __restrict__ p1,
                                                   float* __restrict__ out) {
  size_t i = ((size_t)blockIdx.x * 256 + threadIdx.x) * 4;
  us4 a = *(const us4*)(p1 + i);
  float4 o = *(const float4*)(out + i);
  o.x += bf2f(a.x);
  o.y += bf2f(a.y);
  o.z += bf2f(a.z);
  o.w += bf2f(a.w);
  *(float4*)(out + i) = o;
}

// ------------- Flash attention: 8-wave block, LDS-staged KV, KV-split 2 -----
__global__ void __launch_bounds__(512, 4) attn_kernel(const u16* __restrict__ Qb,
                                                      const u16* __restrict__ Kb,
                                                      const u16* __restrict__ Vt,
                                                      u16* __restrict__ op,
                                                      float2* __restrict__ ml) {
  __shared__ __align__(16) u16 Ks[2][64 * 64];
  __shared__ __align__(16) u16 Vs[2][64 * 64];
  const int bid = blockIdx.x;
  const int bh = bid & 31;
  const int qblk = (bid >> 5) & 7;
  const int part = bid >> 8;
  const int pstart = part * NKV;
  const int tid = threadIdx.x;
  const int w = tid >> 6, lane = tid & 63;
  const int lq = lane & 31, hi = lane >> 5;
  const int q0 = qblk * 256 + w * 32;

  const u16* Qp = Qb + ((size_t)bh * TT + q0 + lq) * HD + hi * 8;
  bf16x8 qf[4];
#pragma unroll
  for (int c = 0; c < 4; c++) qf[c] = *(const bf16x8*)(Qp + c * 16);

  const int srow = tid >> 3, schk = tid & 7;
  const u16* Kg = Kb + ((size_t)bh * TT + pstart + srow) * HD + ((schk ^ (srow & 7)) * 8);
  const u16* Vg = Vt + ((size_t)bh * HD + srow) * TT + pstart + ((schk ^ (srow & 7)) * 8);
  u16* kdst = &Ks[0][0] + tid * 8;
  u16* vdst = &Vs[0][0] + tid * 8;

  int ofs[8];
#pragma unroll
  for (int c = 0; c < 8; c++) ofs[c] = (c ^ (lq & 7)) << 4;

  f32x16 o0, o1;
#pragma unroll
  for (int r = 0; r < 16; r++) { o0[r] = 0.f; o1[r] = 0.f; }
  float m_run = -1e30f, l_run = 0.f;

#define STAGEKV(T, BUF)                                                        \
  do {                                                                         \
    gload_lds16(Kg + (size_t)(T) * 64 * HD, kdst + (BUF) * 4096);              \
    gload_lds16(Vg + (T) * 64, vdst + (BUF) * 4096);                           \
  } while (0)

  STAGEKV(0, 0);
  asm volatile("s_waitcnt vmcnt(0)" ::: "memory");
  __builtin_amdgcn_s_barrier();
  __builtin_amdgcn_sched_barrier(0);

  const int NT = NKV / 64;
  for (int t = 0; t < NT; ++t) {
    const int buf = t & 1;
    if (t + 1 < NT) STAGEKV(t + 1, buf ^ 1);
    const char* kT = (const char*)&Ks[buf][0];
    const char* vT = (const char*)&Vs[buf][0];
#pragma unroll
    for (int ss = 0; ss < 2; ++ss) {
      const char* kR = kT + (ss * 32 + lq) * 128;
      bf16x8 kf[4];
#pragma unroll
      for (int c = 0; c < 4; c++) kf[c] = *(const bf16x8*)(kR + ofs[c * 2 + hi]);
      const char* vR0 = vT + lq * 128;
      const char* vR1 = vT + (32 + lq) * 128;
      bf16x8 v00 = *(const bf16x8*)(vR0 + ofs[ss * 4 + 0 + hi]);
      bf16x8 v01 = *(const bf16x8*)(vR0 + ofs[ss * 4 + 2 + hi]);
      bf16x8 v10 = *(const bf16x8*)(vR1 + ofs[ss * 4 + 0 + hi]);
      bf16x8 v11 = *(const bf16x8*)(vR1 + ofs[ss * 4 + 2 + hi]);
      asm volatile("s_waitcnt lgkmcnt(0)" ::: "memory");
      __builtin_amdgcn_sched_barrier(0);

      f32x16 s;
#pragma unroll
      for (int r = 0; r < 16; r++) s[r] = 0.f;
      __builtin_amdgcn_s_setprio(1);
#pragma unroll
      for (int c = 0; c < 4; c++)
        s = __builtin_amdgcn_mfma_f32_32x32x16_bf16(kf[c], qf[c], s, 0, 0, 0);
      __builtin_amdgcn_s_setprio(0);

      float mx = s[0];
#pragma unroll
      for (int r = 1; r < 16; r++) mx = fmaxf(mx, s[r]);
      mx = fmaxf(mx, __shfl_xor(mx, 32));

      if (__any(mx > m_run + 8.f)) {  // T13 defer-max
        float mn = fmaxf(m_run, mx);
        float al = __expf(m_run - mn);
#pragma unroll
        for (int r = 0; r < 16; r++) { o0[r] *= al; o1[r] *= al; }
        l_run *= al;
        m_run = mn;
      }

      float p[16], ps = 0.f;
#pragma unroll
      for (int r = 0; r < 16; r++) {
        p[r] = __expf(s[r] - m_run);
        ps += p[r];
      }
      l_run += ps + __shfl_xor(ps, 32);

      u32 wv[8];
#pragma unroll
      for (int c = 0; c < 2; c++) {
        u32 qA = cvtpk(p[c * 8 + 0], p[c * 8 + 1]);
        u32 qB = cvtpk(p[c * 8 + 2], p[c * 8 + 3]);
        u32 qC = cvtpk(p[c * 8 + 4], p[c * 8 + 5]);
        u32 qD = cvtpk(p[c * 8 + 6], p[c * 8 + 7]);
        u32 As_ = __shfl_xor(qA, 32), Bs_ = __shfl_xor(qB, 32);
        u32 Cs_ = __shfl_xor(qC, 32), Ds_ = __shfl_xor(qD, 32);
        wv[c * 4 + 0] = hi ? Cs_ : qA;
        wv[c * 4 + 1] = hi ? Ds_ : qB;
        wv[c * 4 + 2] = hi ? qC : As_;
        wv[c * 4 + 3] = hi ? qD : Bs_;
      }
      u32x4 t0 = {wv[0], wv[1], wv[2], wv[3]};
      u32x4 t1 = {wv[4], wv[5], wv[6], wv[7]};
      bf16x8 pf0 = __builtin_bit_cast(bf16x8, t0);
      bf16x8 pf1 = __builtin_bit_cast(bf16x8, t1);

      __builtin_amdgcn_s_setprio(1);
      o0 = __builtin_amdgcn_mfma_f32_32x32x16_bf16(v00, pf0, o0, 0, 0, 0);
      o0 = __builtin_amdgcn_mfma_f32_32x32x16_bf16(v01, pf1, o0, 0, 0, 0);
      o1 = __builtin_amdgcn_mfma_f32_32x32x16_bf16(v10, pf0, o1, 0, 0, 0);
      o1 = __builtin_amdgcn_mfma_f32_32x32x16_bf16(v11, pf1, o1, 0, 0, 0);
      __builtin_amdgcn_s_setprio(0);
    }
    asm volatile("s_waitcnt vmcnt(0)" ::: "memory");
    __builtin_amdgcn_s_barrier();
    __builtin_amdgcn_sched_barrier(0);
  }
#undef STAGEKV

  float rl = 1.f / l_run;
  u16* opP = op + (size_t)part * PO + ((size_t)bh * TT + q0 + lq) * HD;
#pragma unroll
  for (int r = 0; r < 16; r++) {
    int d = (r & 3) + ((r >> 2) << 3) + (hi << 2);
    opP[d] = f2bf(o0[r] * rl);
    opP[32 + d] = f2bf(o1[r] * rl);
  }
  if (hi == 0) {
    float2 v;
    v.x = m_run;
    v.y = l_run;
    ml[(size_t)part * (32 * TT) + bh * TT + q0 + lq] = v;
  }
}

// ------------- attention partial merge -> attn_o [B,T,E] bf16 -------------
__global__ void __launch_bounds__(256) attn_merge(const u16* __restrict__ op,
                                                  const float2* __restrict__ ml,
                                                  u16* __restrict__ O) {
  int idx = blockIdx.x * 256 + threadIdx.x;  // 32*2048*8 total
  int bh = idx >> 14;
  int q = (idx >> 3) & 2047;
  int d0 = (idx & 7) * 8;
  int mli = bh * TT + q;
  float2 ab0 = ml[mli];
  float2 ab1 = ml[32 * TT + mli];
  float ms = fmaxf(ab0.x, ab1.x);
  float w0 = ab0.y * __expf(ab0.x - ms);
  float w1 = ab1.y * __expf(ab1.x - ms);
  float inv = 1.f / (w0 + w1);
  w0 *= inv;
  w1 *= inv;
  size_t base = ((size_t)bh * TT + q) * HD + d0;
  ushort8 a = *(const ushort8*)(op + base);
  ushort8 b = *(const ushort8*)(op + PO + base);
  ushort8 o;
#pragma unroll
  for (int k = 0; k < 8; k++) o[k] = f2bf(w0 * bf2f(a[k]) + w1 * bf2f(b[k]));
  size_t obase = ((size_t)(bh >> 4) * TT + q) * E + (bh & 15) * HD + d0;
  *(ushort8*)(O + obase) = o;
}

extern "C" void kernel_launch(void* const* d_in, const int* in_sizes, int n_in,
                              void* d_out, int out_size, void* d_ws, size_t ws_size,
                              hipStream_t stream) {
  (void)in_sizes; (void)n_in; (void)out_size; (void)ws_size;
  const float* x = (const float*)d_in[0];
  const float* qkv_w = (const float*)d_in[1];
  const float* qkv_b = (const float*)d_in[2];
  const float* out_w = (const float*)d_in[3];
  const float* out_b = (const float*)d_in[4];
  const float* ff_w1 = (const float*)d_in[5];
  const float* ff_b1 = (const float*)d_in[6];
  const float* ff_w2 = (const float*)d_in[7];
  const float* ff_b2 = (const float*)d_in[8];
  const float* ln1_g = (const float*)d_in[9];
  const float* ln1_b = (const float*)d_in[10];
  const float* ln2_g = (const float*)d_in[11];
  const float* ln2_b = (const float*)d_in[12];

  char* ws = (char*)d_ws;
  // liveness-planned layout (<= 80 MiB):
  u16* outwt = (u16*)(ws + 0);           // [0,2M)   live until proj
  u16* ffw1t = (u16*)(ws + 2097152);     // [2,10M)  live until FF1
  u16* ffw2t = (u16*)(ws + 10485760);    // [10,18M) live until FF2
  u16* qkvwt = (u16*)(ws + 18874368);    // [18,24M) dead after QKV gemm
  u16* ln_out = (u16*)(ws + 25165824);   // [24,32M) ln1 (dead after QKV), ln2
  float* x1 = (float*)(ws + 33554432);   // [32,48M) written at proj, live to end
  u16* qb = (u16*)(ws + 50331648);       // [48,56M) dead after attn
  u16* kb = (u16*)(ws + 58720256);       // [56,64M) dead after attn
  u16* vt = (u16*)(ws + 67108864);       // [64,72M) dead after attn
  u16* attn_o = (u16*)(ws + 75497472);   // [72,80M) dead after proj
  u16* opbuf = (u16*)(ws + 18874368);    // [18,34M) attn partials (dead-at-write)
  float2* mlbuf = (float2*)(ws + 35651584);  // [34,35M) attn (m,l), dead before proj
  u16* hbuf = (u16*)(ws + 50331648);     // [48,80M) FF1 out, live through FF2
  u16* pproj = (u16*)(ws + 18874368);    // [18,26M) proj z=1 partial (qkvwt +
                                         //   ln1-head dead; reduce before ln2)
  u16* pbuf = (u16*)(ws + 0);            // [0,8M) FF2 z=1 partial (dead weights)

  transpose4<<<dim3(12288), dim3(32, 8), 0, stream>>>(
      qkv_w, out_w, ff_w1, ff_w2, qkvwt, outwt, ffw1t, ffw2t);

  ln_kernel<<<MMDIM, 256, 0, stream>>>(x, ln1_g, ln1_b, ln_out);
  gemm2pw<0><<<dim3(3072 / 256, MMDIM / 128), 512, 0, stream>>>(
      ln_out, qkvwt, qkv_b, nullptr, qb, kb, vt, nullptr, 3072, 1024, 1024, 1024);
  attn_kernel<<<dim3(2 * 8 * 32), 512, 0, stream>>>(qb, kb, vt, opbuf, mlbuf);
  attn_merge<<<dim3(32 * TT * 8 / 256), 256, 0, stream>>>(opbuf, mlbuf, attn_o);
  // proj: split-K z=2 (Kz=512... K=512 per z, 16 steps of 32)
  gemm2pw<3><<<dim3(1024 / 256, MMDIM / 128, 2), 512, 0, stream>>>(
      attn_o, outwt, out_b, x, pproj, nullptr, nullptr, x1, 1024, 512, 1024, 1024);
  addp_reduce<<<(size_t)MMDIM * E / 1024, 256, 0, stream>>>(pproj, x1);
  ln_kernel<<<MMDIM, 256, 0, stream>>>(x1, ln2_g, ln2_b, ln_out);
  gemm2pw<2><<<dim3(4096 / 256, MMDIM / 128), 512, 0, stream>>>(
      ln_out, ffw1t, ff_b1, nullptr, hbuf, nullptr, nullptr, nullptr, 4096, 1024, 1024, 1024);
  gemm2pw<3><<<dim3(1024 / 256, MMDIM / 128, 2), 512, 0, stream>>>(
      hbuf, ffw2t, ff_b2, x1, pbuf, nullptr, nullptr, (float*)d_out, 1024, 2048, 4096, 4096);
  addp_reduce<<<(size_t)MMDIM * E / 1024, 256, 0, stream>>>(pbuf, (float*)d_out);
}

// Round 16
// 251.319 us; speedup vs baseline: 1.1339x; 1.1339x over previous
//
#include <hip/hip_runtime.h>

#define E     1024
#define HEADS 16
#define HD    64
#define FFD   4096
#define TT    2048
#define MMDIM 4096   // B*T
#define NKV   1024   // KV per attention part (split 2)
#define PO    (32 * 2048 * 64)  // elems per attn O-partial

typedef __bf16 bf16x8 __attribute__((ext_vector_type(8)));
typedef float f32x4 __attribute__((ext_vector_type(4)));
typedef float f32x16 __attribute__((ext_vector_type(16)));
typedef unsigned short u16;
typedef unsigned u32;
typedef u16 ushort8 __attribute__((ext_vector_type(8)));
typedef u16 us4 __attribute__((ext_vector_type(4)));
typedef u32 u32x4 __attribute__((ext_vector_type(4)));

__device__ __forceinline__ u16 f2bf(float f) {
  unsigned u = __float_as_uint(f);
  u = (u + 0x7fffu + ((u >> 16) & 1u)) >> 16;
  return (u16)u;
}
__device__ __forceinline__ float bf2f(u16 u) {
  return __uint_as_float(((unsigned)u) << 16);
}
__device__ __forceinline__ u32 cvtpk(float a, float b) {
  u32 r;
  asm("v_cvt_pk_bf16_f32 %0, %1, %2" : "=v"(r) : "v"(a), "v"(b));
  return r;
}

__device__ __forceinline__ void gload_lds16(const void* g, void* l) {
  __builtin_amdgcn_global_load_lds((__attribute__((address_space(1))) void*)g,
                                   (__attribute__((address_space(3))) void*)l,
                                   16, 0, 0);
}

// ---------------- LayerNorm: fp32 in -> bf16 out ----------------
__global__ void __launch_bounds__(256) ln_kernel(const float* __restrict__ x,
                                                 const float* __restrict__ g,
                                                 const float* __restrict__ b,
                                                 u16* __restrict__ out) {
  int row = blockIdx.x;
  int t = threadIdx.x;
  const float4 v = reinterpret_cast<const float4*>(x + (size_t)row * E)[t];
  float s = v.x + v.y + v.z + v.w;
  float s2 = v.x * v.x + v.y * v.y + v.z * v.z + v.w * v.w;
#pragma unroll
  for (int m = 1; m < 64; m <<= 1) {
    s += __shfl_xor(s, m);
    s2 += __shfl_xor(s2, m);
  }
  __shared__ float red[8];
  int wave = t >> 6, lane = t & 63;
  if (lane == 0) { red[wave] = s; red[wave + 4] = s2; }
  __syncthreads();
  s = red[0] + red[1] + red[2] + red[3];
  s2 = red[4] + red[5] + red[6] + red[7];
  float mean = s * (1.f / E);
  float var = s2 * (1.f / E) - mean * mean;
  float inv = rsqrtf(var + 1e-5f);
  const float4 gv = reinterpret_cast<const float4*>(g)[t];
  const float4 bv = reinterpret_cast<const float4*>(b)[t];
  us4 pk;
  pk.x = f2bf((v.x - mean) * inv * gv.x + bv.x);
  pk.y = f2bf((v.y - mean) * inv * gv.y + bv.y);
  pk.z = f2bf((v.z - mean) * inv * gv.z + bv.z);
  pk.w = f2bf((v.w - mean) * inv * gv.w + bv.w);
  *(us4*)(out + (size_t)row * E + t * 4) = pk;
}

// ------- Fused transpose+convert of all 4 weights: W[K,N] fp32 -> bf16 [N,K]
__global__ void __launch_bounds__(256) transpose4(const float* __restrict__ w0,
                                                  const float* __restrict__ w1,
                                                  const float* __restrict__ w2,
                                                  const float* __restrict__ w3,
                                                  u16* __restrict__ o0,
                                                  u16* __restrict__ o1,
                                                  u16* __restrict__ o2,
                                                  u16* __restrict__ o3) {
  __shared__ float tile[32][33];
  int b = blockIdx.x;
  const float* in;
  u16* out;
  int K, N, bx, by;
  if (b < 3072) {            // qkv_w 1024x3072
    in = w0; out = o0; K = 1024; N = 3072; bx = b % 96; by = b / 96;
  } else if (b < 4096) {     // out_w 1024x1024
    int r = b - 3072; in = w1; out = o1; K = 1024; N = 1024; bx = r % 32; by = r / 32;
  } else if (b < 8192) {     // ff_w1 1024x4096
    int r = b - 4096; in = w2; out = o2; K = 1024; N = 4096; bx = r % 128; by = r / 128;
  } else {                   // ff_w2 4096x1024
    int r = b - 8192; in = w3; out = o3; K = 4096; N = 1024; bx = r % 32; by = r / 32;
  }
  int k0 = by * 32, n0 = bx * 32;
  int tx = threadIdx.x, ty = threadIdx.y;  // block (32,8)
#pragma unroll
  for (int i = ty; i < 32; i += 8)
    tile[i][tx] = in[(size_t)(k0 + i) * N + n0 + tx];
  __syncthreads();
#pragma unroll
  for (int i = ty; i < 32; i += 8)
    out[(size_t)(n0 + i) * K + k0 + tx] = f2bf(tile[tx][i]);
}

// ========== WIDE 2-phase GEMM 128x256, BK=32 (QKV / FF1: big N) ==========
// Staged bytes ∝ (1/BM+1/BN): 25% less than 128^2. 512 thr, 48 KiB LDS,
// occupancy ~43%. 4x8 super-tile XCD map (gx%4==0, gy%8==0).
// MODE 0: +qkv_b, scatter Q(*0.125)/K -> [BH,T,D], V -> [BH,D,T]
// MODE 2: +ff_b1, exact GELU -> bf16 ob0 (stride FFD)
template <int MODE>
__global__ void __launch_bounds__(512) gemm2pw(const u16* __restrict__ Aa,
                                               const u16* __restrict__ Bt,
                                               const float* __restrict__ bias,
                                               u16* __restrict__ ob0,
                                               u16* __restrict__ ob1,
                                               u16* __restrict__ ob2,
                                               int N, int K, int lda, int ldb) {
  __shared__ __align__(16) u16 As[2][128 * 32];
  __shared__ __align__(16) u16 Bs[2][256 * 32];
  const int gx = gridDim.x;
  const int nxy = gx * gridDim.y;
  const int lin = blockIdx.y * gx + blockIdx.x;
  const int g = (lin & 7) * (nxy >> 3) + (lin >> 3);
  const int s = g >> 5, o = g & 31;
  const int gx4 = gx >> 2;
  const int sx = s % gx4, sy = s / gx4;
  const int n0 = (sx * 4 + (o & 3)) * 256;
  const int m0 = (sy * 8 + (o >> 2)) * 128;
  const int tid = threadIdx.x, lane = tid & 63;
  const int w = tid >> 6, wr = w >> 2, wc = w & 3;
  const int l15 = lane & 15, hi4 = lane >> 4;
  const int nt = K >> 5;

  f32x4 acc[4][4];
#pragma unroll
  for (int i = 0; i < 4; i++)
#pragma unroll
    for (int j = 0; j < 4; j++) acc[i][j] = (f32x4){0.f, 0.f, 0.f, 0.f};

  const int arow = tid >> 2, aslot = tid & 3;
  const int asw = (arow & 3) ^ ((arow >> 2) & 3);
  const int brow1 = arow + 128;
  const u16* Ap = Aa + (size_t)(m0 + arow) * lda + (aslot ^ asw) * 8;
  const u16* Bq0 = Bt + (size_t)(n0 + arow) * ldb + (aslot ^ asw) * 8;
  const u16* Bq1 = Bt + (size_t)(n0 + brow1) * ldb + (aslot ^ asw) * 8;

  const int rsw = (l15 & 3) ^ ((l15 >> 2) & 3);
  const int rdofs = (hi4 ^ rsw) << 4;

#define STAGEW(T, BUF)                                                         \
  do {                                                                         \
    int k0_ = (T) << 5;                                                        \
    gload_lds16(Ap + k0_, (char*)&As[BUF][0] + tid * 16);                      \
    gload_lds16(Bq0 + k0_, (char*)&Bs[BUF][0] + tid * 16);                     \
    gload_lds16(Bq1 + k0_, (char*)&Bs[BUF][0] + (tid + 512) * 16);             \
  } while (0)

  STAGEW(0, 0);
  asm volatile("s_waitcnt vmcnt(0)" ::: "memory");
  __builtin_amdgcn_s_barrier();
  __builtin_amdgcn_sched_barrier(0);

  for (int t = 0; t < nt; ++t) {
    const int cur = t & 1;
    if (t + 1 < nt) {
      if (cur == 0) STAGEW(t + 1, 1);
      else          STAGEW(t + 1, 0);
    }
    const char* ab = (const char*)&As[cur][0];
    const char* bb = (const char*)&Bs[cur][0];
    bf16x8 a[4], b[4];
#pragma unroll
    for (int i = 0; i < 4; i++)
      a[i] = *(const bf16x8*)(ab + (wr * 64 + i * 16 + l15) * 64 + rdofs);
#pragma unroll
    for (int j = 0; j < 4; j++)
      b[j] = *(const bf16x8*)(bb + (wc * 64 + j * 16 + l15) * 64 + rdofs);
    asm volatile("s_waitcnt lgkmcnt(0)" ::: "memory");
    __builtin_amdgcn_sched_barrier(0);
    __builtin_amdgcn_s_setprio(1);
#pragma unroll
    for (int i = 0; i < 4; i++)
#pragma unroll
      for (int j = 0; j < 4; j++)
        acc[i][j] = __builtin_amdgcn_mfma_f32_16x16x32_bf16(a[i], b[j], acc[i][j], 0, 0, 0);
    __builtin_amdgcn_s_setprio(0);
    asm volatile("s_waitcnt vmcnt(0)" ::: "memory");
    __builtin_amdgcn_s_barrier();
    __builtin_amdgcn_sched_barrier(0);
  }
#undef STAGEW

#pragma unroll
  for (int i = 0; i < 4; i++) {
#pragma unroll
    for (int j = 0; j < 4; j++) {
      int mb = m0 + wr * 64 + i * 16 + (hi4 << 2);
      int n = n0 + wc * 64 + j * 16 + l15;
      float bv = bias[n];
      float v4[4];
#pragma unroll
      for (int r = 0; r < 4; r++) v4[r] = acc[i][j][r] + bv;
      if (MODE == 0) {
        int b_ = mb >> 11;
        int t = mb & 2047;
        int s_ = n >> 10;
        int hd = n & 1023;
        int h_ = hd >> 6;
        int d = hd & 63;
        size_t bh = (size_t)b_ * HEADS + h_;
        if (s_ == 0) {
#pragma unroll
          for (int r = 0; r < 4; r++)
            ob0[(bh * TT + (t + r)) * HD + d] = f2bf(v4[r] * 0.125f);
        } else if (s_ == 1) {
#pragma unroll
          for (int r = 0; r < 4; r++)
            ob1[(bh * TT + (t + r)) * HD + d] = f2bf(v4[r]);
        } else {
          us4 pk;
#pragma unroll
          for (int r = 0; r < 4; r++) pk[r] = f2bf(v4[r]);
          *(us4*)&ob2[(bh * HD + d) * TT + t] = pk;
        }
      } else {  // MODE 2: exact GELU
#pragma unroll
        for (int r = 0; r < 4; r++)
          ob0[(size_t)(mb + r) * FFD + n] =
              f2bf(0.5f * v4[r] * (1.f + erff(v4[r] * 0.70710678118f)));
      }
    }
  }
}

// ========== 2-phase GEMM 128x128, BK=64, 8x8 super-tile (proj / FF2) ==========
// MODE 3: split-K: z==0 -> of = acc+bias+resid (fp32); z==1 -> bf16 partial ob0
template <int MODE>
__global__ void __launch_bounds__(256) gemm2p(const u16* __restrict__ Aa,
                                              const u16* __restrict__ Bt,
                                              const float* __restrict__ bias,
                                              const float* __restrict__ resid,
                                              u16* __restrict__ ob0,
                                              float* __restrict__ of,
                                              int N, int K, int lda, int ldb) {
  __shared__ __align__(16) u16 As[2][128 * 64];
  __shared__ __align__(16) u16 Bs[2][128 * 64];
  const int nxy = gridDim.x * gridDim.y;
  const int lin = blockIdx.y * gridDim.x + blockIdx.x;
  const int g = (lin & 7) * (nxy >> 3) + (lin >> 3);
  const int s = g >> 6, o = g & 63;
  const int gx8 = gridDim.x >> 3;
  const int sx = s % gx8, sy = s / gx8;
  const int n0 = (sx * 8 + (o & 7)) * 128;
  const int m0 = (sy * 8 + (o >> 3)) * 128;
  const int tid = threadIdx.x, lane = tid & 63;
  const int wave = tid >> 6, wr = wave >> 1, wc = wave & 1;
  const int l15 = lane & 15, hi4 = lane >> 4, l7 = lane & 7;
  const size_t koff = (size_t)blockIdx.z * K;
  const int nt = K >> 6;

  f32x4 acc[4][4];
#pragma unroll
  for (int i = 0; i < 4; i++)
#pragma unroll
    for (int j = 0; j < 4; j++) acc[i][j] = (f32x4){0.f, 0.f, 0.f, 0.f};

  const u16* ApR[4];
  const u16* BpR[4];
#pragma unroll
  for (int r = 0; r < 4; r++) {
    int c = tid + r * 256;
    int row = c >> 3;
    int col = ((c & 7) ^ (row & 7)) * 8;
    ApR[r] = Aa + (size_t)(m0 + row) * lda + koff + col;
    BpR[r] = Bt + (size_t)(n0 + row) * ldb + koff + col;
  }

  const int xk0 = (hi4 << 4) ^ (l7 << 4);
  const int xk1 = (64 + (hi4 << 4)) ^ (l7 << 4);

#define STAGE2P(T, BUF)                                                        \
  do {                                                                         \
    int k0_ = (T) << 6;                                                        \
    _Pragma("unroll") for (int r_ = 0; r_ < 4; r_++) {                         \
      int c_ = tid + r_ * 256;                                                 \
      gload_lds16(ApR[r_] + k0_, &As[BUF][c_ * 8]);                            \
      gload_lds16(BpR[r_] + k0_, &Bs[BUF][c_ * 8]);                            \
    }                                                                          \
  } while (0)

  STAGE2P(0, 0);
  asm volatile("s_waitcnt vmcnt(0)" ::: "memory");
  __builtin_amdgcn_s_barrier();
  __builtin_amdgcn_sched_barrier(0);

  for (int t = 0; t < nt; ++t) {
    const int cur = t & 1;
    if (t + 1 < nt) {
      if (cur == 0) STAGE2P(t + 1, 1);
      else          STAGE2P(t + 1, 0);
    }
    const char* ab = (const char*)&As[0][0] + cur * 16384;
    const char* bb = (const char*)&Bs[0][0] + cur * 16384;
    bf16x8 a0[4], a1[4], b0[4], b1[4];
#pragma unroll
    for (int i = 0; i < 4; i++) {
      int rowb = (wr * 64 + i * 16 + l15) * 128;
      a0[i] = *(const bf16x8*)(ab + rowb + xk0);
      a1[i] = *(const bf16x8*)(ab + rowb + xk1);
    }
#pragma unroll
    for (int j = 0; j < 4; j++) {
      int rowb = (wc * 64 + j * 16 + l15) * 128;
      b0[j] = *(const bf16x8*)(bb + rowb + xk0);
      b1[j] = *(const bf16x8*)(bb + rowb + xk1);
    }
    asm volatile("s_waitcnt lgkmcnt(0)" ::: "memory");
    __builtin_amdgcn_sched_barrier(0);
    __builtin_amdgcn_s_setprio(1);
#pragma unroll
    for (int i = 0; i < 4; i++)
#pragma unroll
      for (int j = 0; j < 4; j++) {
        acc[i][j] = __builtin_amdgcn_mfma_f32_16x16x32_bf16(a0[i], b0[j], acc[i][j], 0, 0, 0);
        acc[i][j] = __builtin_amdgcn_mfma_f32_16x16x32_bf16(a1[i], b1[j], acc[i][j], 0, 0, 0);
      }
    __builtin_amdgcn_s_setprio(0);
    asm volatile("s_waitcnt vmcnt(0)" ::: "memory");
    __builtin_amdgcn_s_barrier();
    __builtin_amdgcn_sched_barrier(0);
  }
#undef STAGE2P

#pragma unroll
  for (int i = 0; i < 4; i++) {
#pragma unroll
    for (int j = 0; j < 4; j++) {
      int mb = m0 + wr * 64 + i * 16 + (hi4 << 2);
      int n = n0 + wc * 64 + j * 16 + l15;
      if (MODE == 3) {
        if (blockIdx.z == 0) {
          float bz = bias[n];
#pragma unroll
          for (int r = 0; r < 4; r++) {
            size_t idx = (size_t)(mb + r) * E + n;
            of[idx] = acc[i][j][r] + bz + resid[idx];
          }
        } else {
#pragma unroll
          for (int r = 0; r < 4; r++)
            ob0[(size_t)(mb + r) * N + n] = f2bf(acc[i][j][r]);
        }
      }
    }
  }
}

// ------------- split-K reduce: out += p (fp32 out, bf16 partial) -------------
__global__ void __launch_bounds__(256) addp_reduce(const u16* __restrict__ p1,
                                                   float* __restrict__ out) {
  size_t i = ((size_t)blockIdx.x * 256 + threadIdx.x) * 4;
  us4 a = *(const us4*)(p1 + i);
  float4 o = *(const float4*)(out + i);
  o.x += bf2f(a.x);
  o.y += bf2f(a.y);
  o.z += bf2f(a.z);
  o.w += bf2f(a.w);
  *(float4*)(out + i) = o;
}

// ------------- Flash attention: 8-wave block, LDS-staged KV, KV-split 2 -----
__global__ void __launch_bounds__(512, 4) attn_kernel(const u16* __restrict__ Qb,
                                                      const u16* __restrict__ Kb,
                                                      const u16* __restrict__ Vt,
                                                      u16* __restrict__ op,
                                                      float2* __restrict__ ml) {
  __shared__ __align__(16) u16 Ks[2][64 * 64];
  __shared__ __align__(16) u16 Vs[2][64 * 64];
  const int bid = blockIdx.x;
  const int bh = bid & 31;
  const int qblk = (bid >> 5) & 7;
  const int part = bid >> 8;
  const int pstart = part * NKV;
  const int tid = threadIdx.x;
  const int w = tid >> 6, lane = tid & 63;
  const int lq = lane & 31, hi = lane >> 5;
  const int q0 = qblk * 256 + w * 32;

  const u16* Qp = Qb + ((size_t)bh * TT + q0 + lq) * HD + hi * 8;
  bf16x8 qf[4];
#pragma unroll
  for (int c = 0; c < 4; c++) qf[c] = *(const bf16x8*)(Qp + c * 16);

  const int srow = tid >> 3, schk = tid & 7;
  const u16* Kg = Kb + ((size_t)bh * TT + pstart + srow) * HD + ((schk ^ (srow & 7)) * 8);
  const u16* Vg = Vt + ((size_t)bh * HD + srow) * TT + pstart + ((schk ^ (srow & 7)) * 8);
  u16* kdst = &Ks[0][0] + tid * 8;
  u16* vdst = &Vs[0][0] + tid * 8;

  int ofs[8];
#pragma unroll
  for (int c = 0; c < 8; c++) ofs[c] = (c ^ (lq & 7)) << 4;

  f32x16 o0, o1;
#pragma unroll
  for (int r = 0; r < 16; r++) { o0[r] = 0.f; o1[r] = 0.f; }
  float m_run = -1e30f, l_run = 0.f;

#define STAGEKV(T, BUF)                                                        \
  do {                                                                         \
    gload_lds16(Kg + (size_t)(T) * 64 * HD, kdst + (BUF) * 4096);              \
    gload_lds16(Vg + (T) * 64, vdst + (BUF) * 4096);                           \
  } while (0)

  STAGEKV(0, 0);
  asm volatile("s_waitcnt vmcnt(0)" ::: "memory");
  __builtin_amdgcn_s_barrier();
  __builtin_amdgcn_sched_barrier(0);

  const int NT = NKV / 64;
  for (int t = 0; t < NT; ++t) {
    const int buf = t & 1;
    if (t + 1 < NT) STAGEKV(t + 1, buf ^ 1);
    const char* kT = (const char*)&Ks[buf][0];
    const char* vT = (const char*)&Vs[buf][0];
#pragma unroll
    for (int ss = 0; ss < 2; ++ss) {
      const char* kR = kT + (ss * 32 + lq) * 128;
      bf16x8 kf[4];
#pragma unroll
      for (int c = 0; c < 4; c++) kf[c] = *(const bf16x8*)(kR + ofs[c * 2 + hi]);
      const char* vR0 = vT + lq * 128;
      const char* vR1 = vT + (32 + lq) * 128;
      bf16x8 v00 = *(const bf16x8*)(vR0 + ofs[ss * 4 + 0 + hi]);
      bf16x8 v01 = *(const bf16x8*)(vR0 + ofs[ss * 4 + 2 + hi]);
      bf16x8 v10 = *(const bf16x8*)(vR1 + ofs[ss * 4 + 0 + hi]);
      bf16x8 v11 = *(const bf16x8*)(vR1 + ofs[ss * 4 + 2 + hi]);
      asm volatile("s_waitcnt lgkmcnt(0)" ::: "memory");
      __builtin_amdgcn_sched_barrier(0);

      f32x16 s;
#pragma unroll
      for (int r = 0; r < 16; r++) s[r] = 0.f;
      __builtin_amdgcn_s_setprio(1);
#pragma unroll
      for (int c = 0; c < 4; c++)
        s = __builtin_amdgcn_mfma_f32_32x32x16_bf16(kf[c], qf[c], s, 0, 0, 0);
      __builtin_amdgcn_s_setprio(0);

      float mx = s[0];
#pragma unroll
      for (int r = 1; r < 16; r++) mx = fmaxf(mx, s[r]);
      mx = fmaxf(mx, __shfl_xor(mx, 32));

      if (__any(mx > m_run + 8.f)) {  // T13 defer-max
        float mn = fmaxf(m_run, mx);
        float al = __expf(m_run - mn);
#pragma unroll
        for (int r = 0; r < 16; r++) { o0[r] *= al; o1[r] *= al; }
        l_run *= al;
        m_run = mn;
      }

      float p[16], ps = 0.f;
#pragma unroll
      for (int r = 0; r < 16; r++) {
        p[r] = __expf(s[r] - m_run);
        ps += p[r];
      }
      l_run += ps + __shfl_xor(ps, 32);

      u32 wv[8];
#pragma unroll
      for (int c = 0; c < 2; c++) {
        u32 qA = cvtpk(p[c * 8 + 0], p[c * 8 + 1]);
        u32 qB = cvtpk(p[c * 8 + 2], p[c * 8 + 3]);
        u32 qC = cvtpk(p[c * 8 + 4], p[c * 8 + 5]);
        u32 qD = cvtpk(p[c * 8 + 6], p[c * 8 + 7]);
        u32 As_ = __shfl_xor(qA, 32), Bs_ = __shfl_xor(qB, 32);
        u32 Cs_ = __shfl_xor(qC, 32), Ds_ = __shfl_xor(qD, 32);
        wv[c * 4 + 0] = hi ? Cs_ : qA;
        wv[c * 4 + 1] = hi ? Ds_ : qB;
        wv[c * 4 + 2] = hi ? qC : As_;
        wv[c * 4 + 3] = hi ? qD : Bs_;
      }
      u32x4 t0 = {wv[0], wv[1], wv[2], wv[3]};
      u32x4 t1 = {wv[4], wv[5], wv[6], wv[7]};
      bf16x8 pf0 = __builtin_bit_cast(bf16x8, t0);
      bf16x8 pf1 = __builtin_bit_cast(bf16x8, t1);

      __builtin_amdgcn_s_setprio(1);
      o0 = __builtin_amdgcn_mfma_f32_32x32x16_bf16(v00, pf0, o0, 0, 0, 0);
      o0 = __builtin_amdgcn_mfma_f32_32x32x16_bf16(v01, pf1, o0, 0, 0, 0);
      o1 = __builtin_amdgcn_mfma_f32_32x32x16_bf16(v10, pf0, o1, 0, 0, 0);
      o1 = __builtin_amdgcn_mfma_f32_32x32x16_bf16(v11, pf1, o1, 0, 0, 0);
      __builtin_amdgcn_s_setprio(0);
    }
    asm volatile("s_waitcnt vmcnt(0)" ::: "memory");
    __builtin_amdgcn_s_barrier();
    __builtin_amdgcn_sched_barrier(0);
  }
#undef STAGEKV

  float rl = 1.f / l_run;
  u16* opP = op + (size_t)part * PO + ((size_t)bh * TT + q0 + lq) * HD;
#pragma unroll
  for (int r = 0; r < 16; r++) {
    int d = (r & 3) + ((r >> 2) << 3) + (hi << 2);
    opP[d] = f2bf(o0[r] * rl);
    opP[32 + d] = f2bf(o1[r] * rl);
  }
  if (hi == 0) {
    float2 v;
    v.x = m_run;
    v.y = l_run;
    ml[(size_t)part * (32 * TT) + bh * TT + q0 + lq] = v;
  }
}

// ------------- attention partial merge -> attn_o [B,T,E] bf16 -------------
__global__ void __launch_bounds__(256) attn_merge(const u16* __restrict__ op,
                                                  const float2* __restrict__ ml,
                                                  u16* __restrict__ O) {
  int idx = blockIdx.x * 256 + threadIdx.x;  // 32*2048*8 total
  int bh = idx >> 14;
  int q = (idx >> 3) & 2047;
  int d0 = (idx & 7) * 8;
  int mli = bh * TT + q;
  float2 ab0 = ml[mli];
  float2 ab1 = ml[32 * TT + mli];
  float ms = fmaxf(ab0.x, ab1.x);
  float w0 = ab0.y * __expf(ab0.x - ms);
  float w1 = ab1.y * __expf(ab1.x - ms);
  float inv = 1.f / (w0 + w1);
  w0 *= inv;
  w1 *= inv;
  size_t base = ((size_t)bh * TT + q) * HD + d0;
  ushort8 a = *(const ushort8*)(op + base);
  ushort8 b = *(const ushort8*)(op + PO + base);
  ushort8 o;
#pragma unroll
  for (int k = 0; k < 8; k++) o[k] = f2bf(w0 * bf2f(a[k]) + w1 * bf2f(b[k]));
  size_t obase = ((size_t)(bh >> 4) * TT + q) * E + (bh & 15) * HD + d0;
  *(ushort8*)(O + obase) = o;
}

extern "C" void kernel_launch(void* const* d_in, const int* in_sizes, int n_in,
                              void* d_out, int out_size, void* d_ws, size_t ws_size,
                              hipStream_t stream) {
  (void)in_sizes; (void)n_in; (void)out_size; (void)ws_size;
  const float* x = (const float*)d_in[0];
  const float* qkv_w = (const float*)d_in[1];
  const float* qkv_b = (const float*)d_in[2];
  const float* out_w = (const float*)d_in[3];
  const float* out_b = (const float*)d_in[4];
  const float* ff_w1 = (const float*)d_in[5];
  const float* ff_b1 = (const float*)d_in[6];
  const float* ff_w2 = (const float*)d_in[7];
  const float* ff_b2 = (const float*)d_in[8];
  const float* ln1_g = (const float*)d_in[9];
  const float* ln1_b = (const float*)d_in[10];
  const float* ln2_g = (const float*)d_in[11];
  const float* ln2_b = (const float*)d_in[12];

  char* ws = (char*)d_ws;
  u16* outwt = (u16*)(ws + 0);           // [0,2M)   live until proj
  u16* ffw1t = (u16*)(ws + 2097152);     // [2,10M)  live until FF1
  u16* ffw2t = (u16*)(ws + 10485760);    // [10,18M) live until FF2
  u16* qkvwt = (u16*)(ws + 18874368);    // [18,24M) dead after QKV gemm
  u16* ln_out = (u16*)(ws + 25165824);   // [24,32M) ln1 (dead after QKV), ln2
  float* x1 = (float*)(ws + 33554432);   // [32,48M) written at proj, live to end
  u16* qb = (u16*)(ws + 50331648);       // [48,56M) dead after attn
  u16* kb = (u16*)(ws + 58720256);       // [56,64M) dead after attn
  u16* vt = (u16*)(ws + 67108864);       // [64,72M) dead after attn
  u16* attn_o = (u16*)(ws + 75497472);   // [72,80M) dead after proj
  u16* opbuf = (u16*)(ws + 18874368);    // [18,34M) attn partials (dead-at-write)
  float2* mlbuf = (float2*)(ws + 35651584);  // [34,35M) attn (m,l)
  u16* hbuf = (u16*)(ws + 50331648);     // [48,80M) FF1 out, live through FF2
  u16* pproj = (u16*)(ws + 18874368);    // [18,26M) proj z=1 partial
  u16* pbuf = (u16*)(ws + 0);            // [0,8M) FF2 z=1 partial (dead weights)

  transpose4<<<dim3(12288), dim3(32, 8), 0, stream>>>(
      qkv_w, out_w, ff_w1, ff_w2, qkvwt, outwt, ffw1t, ffw2t);

  ln_kernel<<<MMDIM, 256, 0, stream>>>(x, ln1_g, ln1_b, ln_out);
  gemm2pw<0><<<dim3(3072 / 256, MMDIM / 128), 512, 0, stream>>>(
      ln_out, qkvwt, qkv_b, qb, kb, vt, 3072, 1024, 1024, 1024);
  attn_kernel<<<dim3(2 * 8 * 32), 512, 0, stream>>>(qb, kb, vt, opbuf, mlbuf);
  attn_merge<<<dim3(32 * TT * 8 / 256), 256, 0, stream>>>(opbuf, mlbuf, attn_o);
  // proj: 128x128, split-K z=2 -> 512 blocks = 2/CU
  gemm2p<3><<<dim3(1024 / 128, MMDIM / 128, 2), 256, 0, stream>>>(
      attn_o, outwt, out_b, x, pproj, x1, 1024, 512, 1024, 1024);
  addp_reduce<<<(size_t)MMDIM * E / 1024, 256, 0, stream>>>(pproj, x1);
  ln_kernel<<<MMDIM, 256, 0, stream>>>(x1, ln2_g, ln2_b, ln_out);
  gemm2pw<2><<<dim3(4096 / 256, MMDIM / 128), 512, 0, stream>>>(
      ln_out, ffw1t, ff_b1, hbuf, nullptr, nullptr, 4096, 1024, 1024, 1024);
  // FF2: 128x128, split-K z=2 -> 512 blocks = 2/CU
  gemm2p<3><<<dim3(1024 / 128, MMDIM / 128, 2), 256, 0, stream>>>(
      hbuf, ffw2t, ff_b2, x1, pbuf, (float*)d_out, 1024, 2048, 4096, 4096);
  addp_reduce<<<(size_t)MMDIM * E / 1024, 256, 0, stream>>>(pbuf, (float*)d_out);
}